// Round 7
// baseline (303.811 us; speedup 1.0000x reference)
//
#include <hip/hip_runtime.h>
#include <math.h>

// ADIOS contrastive loss, MI355X — fp16 MFMA, 256^2-tile 8-phase schedule
// (T2 LDS swizzle + T3/T4 counted-vmcnt pipeline + T5 setprio).
// K=512 -> 8 K-tiles of BK=64, each staged as 4 half-units (A/B x k-half,
// 2 global_load_lds per thread each). Steady state: 3 half-units (6 loads)
// in flight; vmcnt(6) only at phases 4 and 8; vmcnt(0) only in the drain iter.

#define B_ROWS 4096
#define M_MASK 4
#define D_DIM  512
#define N_COLS ((M_MASK + 1) * B_ROWS)   // 20480
#define GK     D_DIM                     // 512 fp16

typedef _Float16 f16x8 __attribute__((ext_vector_type(8)));
typedef float    f32x4 __attribute__((ext_vector_type(4)));

__device__ __forceinline__ float inv_temp(const int* __restrict__ itp) {
    int it = *itp;
    double T;
    if (it >= 300000) {
        T = 0.05;
    } else {
        double p = (double)it / 300000.0;
        T = 0.05 + 0.5 * (0.2 - 0.05) * (1.0 + cos(3.14159265358979323846 * p));
    }
    return (float)(1.0 / T);
}

// One wave per row: L2-normalize, cast fp16, store [N_COLS][GK].
__global__ __launch_bounds__(256) void prep_kernel(
        const float* __restrict__ orig, const float* __restrict__ masked,
        _Float16* __restrict__ E) {
    int gw = blockIdx.x * 4 + (threadIdx.x >> 6);
    int l  = threadIdx.x & 63;
    if (gw >= N_COLS) return;
    const float* row = (gw < B_ROWS) ? orig + (size_t)gw * D_DIM
                                     : masked + (size_t)(gw - B_ROWS) * D_DIM;
    float4 a = *(const float4*)(row + l * 8);
    float4 b = *(const float4*)(row + l * 8 + 4);
    float s = a.x*a.x + a.y*a.y + a.z*a.z + a.w*a.w
            + b.x*b.x + b.y*b.y + b.z*b.z + b.w*b.w;
    #pragma unroll
    for (int off = 1; off < 64; off <<= 1) s += __shfl_xor(s, off, 64);
    float inv = 1.0f / fmaxf(sqrtf(s), 1e-12f);

    f16x8 h;
    h[0] = (_Float16)(a.x*inv); h[1] = (_Float16)(a.y*inv);
    h[2] = (_Float16)(a.z*inv); h[3] = (_Float16)(a.w*inv);
    h[4] = (_Float16)(b.x*inv); h[5] = (_Float16)(b.y*inv);
    h[6] = (_Float16)(b.z*inv); h[7] = (_Float16)(b.w*inv);
    *(f16x8*)(E + (size_t)gw * GK + l * 8) = h;
}

// 256x256 tile, 8 waves (2 row x 4 col), per-wave 128x64 output.
// LDS: A [2 slot][2 kh][256 r][32 k] f16 (64 KiB) then B same (64 KiB).
__global__ __launch_bounds__(512, 2) void gemm_kernel(
        const _Float16* __restrict__ E, const int* __restrict__ itp,
        float* __restrict__ denom, float* __restrict__ pos) {
    __shared__ _Float16 LDS[65536];   // 128 KiB

    const int tid = threadIdx.x;
    const int l   = tid & 63;
    const int wid = tid >> 6;
    const int wr  = wid >> 2;          // 0..1: wave row-half (128 rows)
    const int wc  = wid & 3;           // 0..3: wave col-quarter (64 cols)

    const int rt = blockIdx.x / (N_COLS / 256);   // consecutive blocks share A-panel
    const int ct = blockIdx.x % (N_COLS / 256);
    const int rowBase = rt * 256;
    const int colBase = ct * 256;

    // Stage one half-unit: matrix (A|B), K-tile t, k-half h -> slot t&1.
    // LDS dest linear (wave-uniform base + lane*16); swizzle applied on the
    // GLOBAL source k-offset (involution: kf_src = kf_lin ^ ((r>>1&3)*8)).
    auto STAGE = [&](int isB, int t, int h) {
        const int panel = isB ? colBase : rowBase;
        _Float16* base = LDS + (isB ? 32768 : 0) + (((t & 1) * 2 + h) * 8192);
        const int tFull = t * 64 + h * 32;
        #pragma unroll
        for (int i = 0; i < 2; ++i) {
            const int o16 = tid * 8 + i * 4096;       // f16 offset in 16KB region
            const int r   = o16 >> 5;                 // 32 f16 per row
            const int ks  = ((tid & 3) * 8) ^ (((r >> 1) & 3) * 8);
            const _Float16* src = E + (size_t)(panel + r) * GK + tFull + ks;
            __builtin_amdgcn_global_load_lds(
                (const __attribute__((address_space(1))) void*)src,
                (__attribute__((address_space(3))) void*)(base + o16), 16, 0, 0);
        }
    };

    f16x8 af[8], bf[2];
    auto LDA = [&](int slot, int h) {
        const _Float16* base = LDS + (slot * 2 + h) * 8192;
        #pragma unroll
        for (int m = 0; m < 8; ++m) {
            const int r = wr * 128 + m * 16 + (l & 15);
            af[m] = *(const f16x8*)(base + r * 32 + (((l >> 4) * 8) ^ (((r >> 1) & 3) * 8)));
        }
    };
    auto LDB = [&](int slot, int h, int nh) {
        const _Float16* base = LDS + 32768 + (slot * 2 + h) * 8192;
        #pragma unroll
        for (int n = 0; n < 2; ++n) {
            const int c = wc * 64 + nh * 32 + n * 16 + (l & 15);
            bf[n] = *(const f16x8*)(base + c * 32 + (((l >> 4) * 8) ^ (((c >> 1) & 3) * 8)));
        }
    };

    f32x4 acc[8][4];
    #pragma unroll
    for (int m = 0; m < 8; ++m)
        #pragma unroll
        for (int n = 0; n < 4; ++n)
            #pragma unroll
            for (int j = 0; j < 4; ++j) acc[m][n][j] = 0.f;

    auto MM = [&](int nh) {
        __builtin_amdgcn_s_setprio(1);
        #pragma unroll
        for (int m = 0; m < 8; ++m)
            #pragma unroll
            for (int n = 0; n < 2; ++n)
                acc[m][nh * 2 + n] = __builtin_amdgcn_mfma_f32_16x16x32_f16(
                    af[m], bf[n], acc[m][nh * 2 + n], 0, 0, 0);
        __builtin_amdgcn_s_setprio(0);
    };

#define BAR()       __builtin_amdgcn_s_barrier()
#define WAIT_LGKM() { asm volatile("s_waitcnt lgkmcnt(0)" ::: "memory"); \
                      __builtin_amdgcn_sched_barrier(0); }
#define VM6()       asm volatile("s_waitcnt vmcnt(6)" ::: "memory")
#define VM0()       asm volatile("s_waitcnt vmcnt(0)" ::: "memory")

    // Prologue: stage tile0 fully + 3 halves of tile1; wait tile0 (vmcnt(6)).
    STAGE(0,0,0); STAGE(1,0,0); STAGE(0,0,1); STAGE(1,0,1);
    STAGE(0,1,0); STAGE(1,1,0); STAGE(0,1,1);
    VM6();
    BAR();

    // Main iters: K-tiles (2i, 2i+1); prefetch (2i+2, 2i+3).
    for (int i = 0; i < 3; ++i) {
        const int t2 = 2 * i + 2, t3 = 2 * i + 3;
        // tile 2i (slot 0)
        LDA(0,0); LDB(0,0,0); STAGE(1, 2*i+1, 1); BAR(); WAIT_LGKM(); MM(0); BAR();
        LDB(0,0,1);           STAGE(0, t2, 0);    BAR(); WAIT_LGKM(); MM(1); BAR();
        LDA(0,1); LDB(0,1,0); STAGE(1, t2, 0);    BAR(); WAIT_LGKM(); MM(0); BAR();
        LDB(0,1,1);           STAGE(0, t2, 1);    BAR(); WAIT_LGKM(); MM(1); VM6(); BAR();
        // tile 2i+1 (slot 1)
        LDA(1,0); LDB(1,0,0); STAGE(1, t2, 1);    BAR(); WAIT_LGKM(); MM(0); BAR();
        LDB(1,0,1);           STAGE(0, t3, 0);    BAR(); WAIT_LGKM(); MM(1); BAR();
        LDA(1,1); LDB(1,1,0); STAGE(1, t3, 0);    BAR(); WAIT_LGKM(); MM(0); BAR();
        LDB(1,1,1);           STAGE(0, t3, 1);    BAR(); WAIT_LGKM(); MM(1); VM6(); BAR();
    }
    // Drain iter: K-tiles 6,7; only tile7's last half left to stage.
    LDA(0,0); LDB(0,0,0); STAGE(1, 7, 1); BAR(); WAIT_LGKM(); MM(0); BAR();
    LDB(0,0,1);                           BAR(); WAIT_LGKM(); MM(1); BAR();
    LDA(0,1); LDB(0,1,0);                 BAR(); WAIT_LGKM(); MM(0); BAR();
    LDB(0,1,1);                           BAR(); WAIT_LGKM(); MM(1); VM0(); BAR();
    LDA(1,0); LDB(1,0,0);                 BAR(); WAIT_LGKM(); MM(0); BAR();
    LDB(1,0,1);                           BAR(); WAIT_LGKM(); MM(1); BAR();
    LDA(1,1); LDB(1,1,0);                 BAR(); WAIT_LGKM(); MM(0); BAR();
    LDB(1,1,1);                           BAR(); WAIT_LGKM(); MM(1);

    // Epilogue: e = exp(sim*invT) (diag -> 0); row-sums + positives.
    const float scale = inv_temp(itp) * 1.44269504088896340736f;  // exp2
    #pragma unroll
    for (int m = 0; m < 8; ++m) {
        float ds[4] = {0.f, 0.f, 0.f, 0.f};
        #pragma unroll
        for (int n = 0; n < 4; ++n) {
            const int col = colBase + wc * 64 + n * 16 + (l & 15);
            #pragma unroll
            for (int q = 0; q < 4; ++q) {
                const int row = rowBase + wr * 128 + m * 16 + (l >> 4) * 4 + q;
                float e = exp2f(acc[m][n][q] * scale);
                if (col == row) e = 0.f;
                ds[q] += e;
                const int d = col - row;
                if (d > 0 && (d & (B_ROWS - 1)) == 0) atomicAdd(&pos[row], e);
            }
        }
        #pragma unroll
        for (int q = 0; q < 4; ++q) {
            #pragma unroll
            for (int off = 1; off < 16; off <<= 1)
                ds[q] += __shfl_xor(ds[q], off, 64);
        }
        if ((l & 15) == 0) {
            #pragma unroll
            for (int q = 0; q < 4; ++q)
                atomicAdd(&denom[rowBase + wr * 128 + m * 16 + (l >> 4) * 4 + q], ds[q]);
        }
    }
#undef BAR
#undef WAIT_LGKM
#undef VM6
#undef VM0
}

__global__ __launch_bounds__(256) void loss_kernel(
        const float* __restrict__ denom, const float* __restrict__ pos,
        float* __restrict__ out) {
    __shared__ double buf[256];
    double s = 0.0;
    for (int i = threadIdx.x; i < B_ROWS; i += 256) {
        float p = pos[i];
        float d = denom[i] + 1e-8f;
        s += (double)(-logf(p / d));
    }
    buf[threadIdx.x] = s;
    __syncthreads();
    for (int off = 128; off >= 1; off >>= 1) {
        if (threadIdx.x < off) buf[threadIdx.x] += buf[threadIdx.x + off];
        __syncthreads();
    }
    if (threadIdx.x == 0) out[0] = (float)(buf[0] / (double)B_ROWS);
}

extern "C" void kernel_launch(void* const* d_in, const int* in_sizes, int n_in,
                              void* d_out, int out_size, void* d_ws, size_t ws_size,
                              hipStream_t stream) {
    const float* orig   = (const float*)d_in[0];   // [B, D]
    const float* masked = (const float*)d_in[1];   // [M, B, D]
    const int*   itp    = (const int*)d_in[2];     // [1]

    _Float16* E   = (_Float16*)d_ws;                       // [N_COLS][GK] ~20 MB
    float* denom  = (float*)(E + (size_t)N_COLS * GK);     // [B]
    float* pos    = denom + B_ROWS;                        // [B]
    float* out    = (float*)d_out;

    hipMemsetAsync(denom, 0, 2 * B_ROWS * sizeof(float), stream);

    prep_kernel<<<N_COLS / 4, 256, 0, stream>>>(orig, masked, E);

    gemm_kernel<<<(B_ROWS / 256) * (N_COLS / 256), 512, 0, stream>>>(E, itp, denom, pos);

    loss_kernel<<<1, 256, 0, stream>>>(denom, pos, out);
}

// Round 8
// 209.288 us; speedup vs baseline: 1.4516x; 1.4516x over previous
//
#include <hip/hip_runtime.h>
#include <math.h>

// ADIOS contrastive loss, MI355X — fp16 MFMA (K=512), 128^2 tile, 4 waves,
// TRIPLE-buffered LDS + counted vmcnt(4) + raw s_barrier (no full drains).
// R6 baseline: 641 TF, MfmaUtil 27.8, stalled on __syncthreads vmcnt(0) drains.
// R7 lesson: 1 block/CU lockstep (256^2/128KiB) starves the CU — keep 3 blocks/CU.

#define B_ROWS 4096
#define M_MASK 4
#define D_DIM  512
#define N_COLS ((M_MASK + 1) * B_ROWS)   // 20480
#define GK     D_DIM                     // 512 fp16
#define NT     (GK / 32)                 // 16 K-tiles

typedef _Float16 f16x8 __attribute__((ext_vector_type(8)));
typedef float    f32x4 __attribute__((ext_vector_type(4)));

__device__ __forceinline__ float inv_temp(const int* __restrict__ itp) {
    int it = *itp;
    double T;
    if (it >= 300000) {
        T = 0.05;
    } else {
        double p = (double)it / 300000.0;
        T = 0.05 + 0.5 * (0.2 - 0.05) * (1.0 + cos(3.14159265358979323846 * p));
    }
    return (float)(1.0 / T);
}

// One wave per row: L2-normalize, cast fp16, store [N_COLS][GK].
__global__ __launch_bounds__(256) void prep_kernel(
        const float* __restrict__ orig, const float* __restrict__ masked,
        _Float16* __restrict__ E) {
    int gw = blockIdx.x * 4 + (threadIdx.x >> 6);
    int l  = threadIdx.x & 63;
    if (gw >= N_COLS) return;
    const float* row = (gw < B_ROWS) ? orig + (size_t)gw * D_DIM
                                     : masked + (size_t)(gw - B_ROWS) * D_DIM;
    float4 a = *(const float4*)(row + l * 8);
    float4 b = *(const float4*)(row + l * 8 + 4);
    float s = a.x*a.x + a.y*a.y + a.z*a.z + a.w*a.w
            + b.x*b.x + b.y*b.y + b.z*b.z + b.w*b.w;
    #pragma unroll
    for (int off = 1; off < 64; off <<= 1) s += __shfl_xor(s, off, 64);
    float inv = 1.0f / fmaxf(sqrtf(s), 1e-12f);

    f16x8 h;
    h[0] = (_Float16)(a.x*inv); h[1] = (_Float16)(a.y*inv);
    h[2] = (_Float16)(a.z*inv); h[3] = (_Float16)(a.w*inv);
    h[4] = (_Float16)(b.x*inv); h[5] = (_Float16)(b.y*inv);
    h[6] = (_Float16)(b.z*inv); h[7] = (_Float16)(b.w*inv);
    *(f16x8*)(E + (size_t)gw * GK + l * 8) = h;
}

// 128x128 tile, 4 waves (2x2), per-wave 64x64. 3 LDS slots of (A 128x32 | B 128x32).
__global__ __launch_bounds__(256, 3) void gemm_kernel(
        const _Float16* __restrict__ E, const int* __restrict__ itp,
        float* __restrict__ denom, float* __restrict__ pos) {
    __shared__ _Float16 LDS[3 * 8192];   // 48 KiB: slot = A[128][32] + B[128][32]

    const int tid = threadIdx.x;
    const int l   = tid & 63;
    const int wid = tid >> 6;
    const int wr  = wid >> 1;
    const int wc  = wid & 1;

    const int rowTile = blockIdx.x & 31;     // 4096/128
    const int colTile = blockIdx.x >> 5;     // 20480/128
    const int rowBase = rowTile * 128;
    const int colBase = colTile * 128;

    const _Float16* Ag = E + (size_t)rowBase * GK;
    const _Float16* Bg = E + (size_t)colBase * GK;

    // Stage K-tile t (A+B, 16 KB) into slot t%3. 4 gload_lds per thread.
    auto STAGE = [&](int t) {
        _Float16* base = LDS + (t % 3) * 8192;
        const int kb = t * 32;
        #pragma unroll
        for (int i = 0; i < 2; ++i) {
            const int rc = wid * 32 + i * 16;             // 16-row chunk
            const int r  = rc + (l >> 2);
            const size_t go = (size_t)r * GK + kb + (l & 3) * 8;
            __builtin_amdgcn_global_load_lds(
                (const __attribute__((address_space(1))) void*)(Ag + go),
                (__attribute__((address_space(3))) void*)(base + rc * 32), 16, 0, 0);
            __builtin_amdgcn_global_load_lds(
                (const __attribute__((address_space(1))) void*)(Bg + go),
                (__attribute__((address_space(3))) void*)(base + 4096 + rc * 32), 16, 0, 0);
        }
    };

    f16x8 af[4], bf[4];
    auto FRAGS = [&](int t) {
        const _Float16* base = LDS + (t % 3) * 8192;
        #pragma unroll
        for (int m = 0; m < 4; ++m)
            af[m] = *(const f16x8*)(base + (wr * 64 + m * 16 + (l & 15)) * 32 + (l >> 4) * 8);
        #pragma unroll
        for (int n = 0; n < 4; ++n)
            bf[n] = *(const f16x8*)(base + 4096 + (wc * 64 + n * 16 + (l & 15)) * 32 + (l >> 4) * 8);
    };

    f32x4 acc[4][4];
    #pragma unroll
    for (int m = 0; m < 4; ++m)
        #pragma unroll
        for (int n = 0; n < 4; ++n)
            #pragma unroll
            for (int j = 0; j < 4; ++j) acc[m][n][j] = 0.f;

    auto MM = [&]() {
        __builtin_amdgcn_s_setprio(1);
        #pragma unroll
        for (int m = 0; m < 4; ++m)
            #pragma unroll
            for (int n = 0; n < 4; ++n)
                acc[m][n] = __builtin_amdgcn_mfma_f32_16x16x32_f16(af[m], bf[n], acc[m][n], 0, 0, 0);
        __builtin_amdgcn_s_setprio(0);
    };

#define BAR()  __builtin_amdgcn_s_barrier()
#define LGKM0() { asm volatile("s_waitcnt lgkmcnt(0)" ::: "memory"); \
                  __builtin_amdgcn_sched_barrier(0); }
#define VM(n)  asm volatile("s_waitcnt vmcnt(" #n ")" ::: "memory")

    // Prologue: stage tiles 0,1; drain tile 0.
    STAGE(0); STAGE(1);
    VM(4);
    BAR();

    // Steady: iter t reads slot t%3, stages t+2, drains t+1 (issued a full
    // iter earlier). WAR on slot (t+2)%3 = slot (t-1)%3 protected by the
    // previous iter's closing barrier (readers' lgkmcnt(0) precedes it).
    for (int t = 0; t < NT - 2; ++t) {
        STAGE(t + 2);
        FRAGS(t);
        VM(4);            // tile t+1 complete for next iter
        BAR();
        LGKM0();
        MM();
        BAR();
    }
    // Tail: t = NT-2 (drain last tile), then t = NT-1.
    FRAGS(NT - 2);
    VM(0);
    BAR();
    LGKM0();
    MM();
    BAR();
    FRAGS(NT - 1);
    LGKM0();
    MM();

    // Epilogue: e = exp(sim*invT) (diag -> 0); row-sums + positives.
    const float scale = inv_temp(itp) * 1.44269504088896340736f;  // exp2
    float dsum[16];
    #pragma unroll
    for (int i = 0; i < 16; ++i) dsum[i] = 0.f;

    #pragma unroll
    for (int m = 0; m < 4; ++m) {
        #pragma unroll
        for (int n = 0; n < 4; ++n) {
            const int col = colBase + wc * 64 + n * 16 + (l & 15);
            #pragma unroll
            for (int r = 0; r < 4; ++r) {
                const int row = rowBase + wr * 64 + m * 16 + (l >> 4) * 4 + r;
                float e = exp2f(acc[m][n][r] * scale);
                if (col == row) e = 0.f;
                dsum[m * 4 + r] += e;
                const int d = col - row;
                if (d > 0 && (d & (B_ROWS - 1)) == 0) atomicAdd(&pos[row], e);
            }
        }
    }
    #pragma unroll
    for (int i = 0; i < 16; ++i) {
        #pragma unroll
        for (int off = 1; off < 16; off <<= 1)
            dsum[i] += __shfl_xor(dsum[i], off, 64);
    }
    if ((l & 15) == 0) {
        #pragma unroll
        for (int i = 0; i < 16; ++i) {
            const int row = rowBase + wr * 64 + (i >> 2) * 16 + (l >> 4) * 4 + (i & 3);
            atomicAdd(&denom[row], dsum[i]);
        }
    }
#undef BAR
#undef LGKM0
#undef VM
}

__global__ __launch_bounds__(256) void loss_kernel(
        const float* __restrict__ denom, const float* __restrict__ pos,
        float* __restrict__ out) {
    __shared__ double buf[256];
    double s = 0.0;
    for (int i = threadIdx.x; i < B_ROWS; i += 256) {
        float p = pos[i];
        float d = denom[i] + 1e-8f;
        s += (double)(-logf(p / d));
    }
    buf[threadIdx.x] = s;
    __syncthreads();
    for (int off = 128; off >= 1; off >>= 1) {
        if (threadIdx.x < off) buf[threadIdx.x] += buf[threadIdx.x + off];
        __syncthreads();
    }
    if (threadIdx.x == 0) out[0] = (float)(buf[0] / (double)B_ROWS);
}

extern "C" void kernel_launch(void* const* d_in, const int* in_sizes, int n_in,
                              void* d_out, int out_size, void* d_ws, size_t ws_size,
                              hipStream_t stream) {
    const float* orig   = (const float*)d_in[0];   // [B, D]
    const float* masked = (const float*)d_in[1];   // [M, B, D]
    const int*   itp    = (const int*)d_in[2];     // [1]

    _Float16* E   = (_Float16*)d_ws;                       // [N_COLS][GK] ~20 MB
    float* denom  = (float*)(E + (size_t)N_COLS * GK);     // [B]
    float* pos    = denom + B_ROWS;                        // [B]
    float* out    = (float*)d_out;

    hipMemsetAsync(denom, 0, 2 * B_ROWS * sizeof(float), stream);

    prep_kernel<<<N_COLS / 4, 256, 0, stream>>>(orig, masked, E);

    gemm_kernel<<<(B_ROWS / 128) * (N_COLS / 128), 256, 0, stream>>>(E, itp, denom, pos);

    loss_kernel<<<1, 256, 0, stream>>>(denom, pos, out);
}